// Round 1
// baseline (164.709 us; speedup 1.0000x reference)
//
#include <hip/hip_runtime.h>
#include <hip/hip_bf16.h>

// PairwiseScore: B=2, N=256, E=512, H=150 (padded to 160)
// out[b,i,j] = (m[b,i] + m[b,j] + MLP3(g_i, g_j)) / 3
//
// Key fold: hij + hj = sum_e (g_i[e]*W1c[e,h] + W1b[e,h]) * g_j[e]
// -> per-block A-operand built per K-tile in LDS (MFMA A-frag layout),
//    B-operand = raw bf16 g rows from global (L2-resident).
// GEMM1 (16x16x32 bf16): D1[h][j]; epilogue relu(+hi+b1) kept in registers.
// GEMM2: D2 = W2^T * h1 ; h1 C-layout -> B-frag layout via 8 shfl + selects.
// GEMM3: per-lane FMA with W3 + shfl_xor reduce over quads.

typedef __attribute__((ext_vector_type(4))) float f32x4;
typedef __attribute__((ext_vector_type(4))) unsigned int u32x4;
typedef __attribute__((ext_vector_type(2))) unsigned int u32x2;
typedef __attribute__((ext_vector_type(8))) short short8;

#define NB 2
#define NN 256
#define NE 512
#define NH 150
#define HP 160      // padded H
#define NKT 16      // NE/32 k-tiles for GEMM1
#define NHT 10      // HP/16 h-tiles
#define NS 5        // HP/32 k-steps for GEMM2

// ---------- helpers ----------
__device__ __forceinline__ unsigned pk_bf16(float a, float b) {
  // round-to-nearest-even bf16 pack (RNE matters: truncation bias ~0.03 over 512-term sums)
  unsigned ua = __builtin_bit_cast(unsigned, a);
  unsigned ub = __builtin_bit_cast(unsigned, b);
  ua += 0x7fffu + ((ua >> 16) & 1u);
  ub += 0x7fffu + ((ub >> 16) & 1u);
  return (ua >> 16) | (ub & 0xffff0000u);
}
__device__ __forceinline__ float bf_lo(unsigned u) { return __builtin_bit_cast(float, u << 16); }
__device__ __forceinline__ float bf_hi(unsigned u) { return __builtin_bit_cast(float, u & 0xffff0000u); }

// ---------- prep: pack weights/activations into frag-major bf16 ----------
// grid 309 x 256:
//  bid [0,256)    : g (f32) -> g_bf16
//  bid [256,296)  : W1b/W1c -> WbF/WcF frag-major [(kt*10+ht)*64+lane]*8
//  bid [296,309)  : W2^T -> W2TF frag-major [(s*10+ht)*64+lane]*8
__global__ __launch_bounds__(256) void prep_pack(
    const float* __restrict__ g, const float* __restrict__ W1,
    const float* __restrict__ W2,
    unsigned short* __restrict__ g_bf16, unsigned short* __restrict__ WbF,
    unsigned short* __restrict__ WcF, unsigned short* __restrict__ W2TF)
{
  int bid = blockIdx.x, tid = threadIdx.x;
  if (bid < 256) {
    int t = bid * 256 + tid;                 // 65536 float4s = 262144 floats
    f32x4 v = ((const f32x4*)g)[t];
    u32x2 o; o[0] = pk_bf16(v[0], v[1]); o[1] = pk_bf16(v[2], v[3]);
    ((u32x2*)g_bf16)[t] = o;
  } else if (bid < 296) {
    int row = (bid - 256) * 256 + tid;       // 0..10239 = 16kt*10ht*64lane
    int kt = row / 640; int rem = row - kt * 640;
    int l = rem & 63; int chh = rem >> 6;
    int e = kt * 32 + (l >> 4) * 8;          // 8 consecutive e per lane-row
    int h = chh * 16 + (l & 15);
    u32x4 ob, oc;
#pragma unroll
    for (int q = 0; q < 4; ++q) {
      int e0 = e + 2 * q, e1 = e0 + 1;
      float vb0 = 0.f, vb1 = 0.f, vc0 = 0.f, vc1 = 0.f;
      if (h < NH) {
        vb0 = W1[(512 + e0) * NH + h]; vb1 = W1[(512 + e1) * NH + h];
        vc0 = W1[(1024 + e0) * NH + h]; vc1 = W1[(1024 + e1) * NH + h];
      }
      ob[q] = pk_bf16(vb0, vb1); oc[q] = pk_bf16(vc0, vc1);
    }
    ((u32x4*)WbF)[row] = ob;
    ((u32x4*)WcF)[row] = oc;
  } else {
    int row = (bid - 296) * 256 + tid;       // < 3200 = 5s*10ht*64lane
    if (row < 3200) {
      int s = row / 640; int rem = row - s * 640;
      int l = rem & 63; int chh = rem >> 6;
      int k = s * 32 + (l >> 4) * 8;         // k = h (input of layer2)
      int hp = chh * 16 + (l & 15);          // m = h' (output of layer2)
      u32x4 o;
#pragma unroll
      for (int q = 0; q < 4; ++q) {
        int k0 = k + 2 * q, k1 = k0 + 1;
        float v0 = (k0 < NH && hp < NH) ? W2[k0 * NH + hp] : 0.f;
        float v1 = (k1 < NH && hp < NH) ? W2[k1 * NH + hp] : 0.f;
        o[q] = pk_bf16(v0, v1);
      }
      ((u32x4*)W2TF)[row] = o;
    }
  }
}

// ---------- prep: hi[b,n,h] = sum_e g[b,n,e] * W1a[e,h], padded to HP ----------
__global__ __launch_bounds__(256) void prep_hi(
    const float* __restrict__ g, const float* __restrict__ W1,
    float* __restrict__ hi_pad)
{
  __shared__ float gs[8 * NE];               // 8 rows staged (16 KB)
  int bid = blockIdx.x;                      // 0..63, 8 rows each
  int tid = threadIdx.x;
  const f32x4* gsrc = (const f32x4*)(g + (size_t)bid * 8 * NE);
  f32x4* gd = (f32x4*)gs;
  for (int idx = tid; idx < 1024; idx += 256) gd[idx] = gsrc[idx];
  __syncthreads();
  if (tid < HP) {
    int h = tid;
    float acc[8] = {0.f,0.f,0.f,0.f,0.f,0.f,0.f,0.f};
    if (h < NH) {
      for (int e = 0; e < NE; ++e) {
        float w = W1[e * NH + h];            // W1a rows 0..511, coalesced over h
#pragma unroll
        for (int r = 0; r < 8; ++r) acc[r] += gs[r * NE + e] * w;
      }
    }
#pragma unroll
    for (int r = 0; r < 8; ++r) hi_pad[(size_t)(bid * 8 + r) * HP + h] = acc[r];
  }
}

// ---------- main fused kernel: one block per (b,i), 512 threads ----------
__global__ __launch_bounds__(512, 2) void pair_main(
    const float* __restrict__ mention, const float* __restrict__ b1,
    const float* __restrict__ b2, const float* __restrict__ W3,
    const float* __restrict__ b3,
    const unsigned short* __restrict__ g_bf16,
    const unsigned short* __restrict__ WbF, const unsigned short* __restrict__ WcF,
    const unsigned short* __restrict__ W2TF, const float* __restrict__ hi_pad,
    float* __restrict__ out)
{
  __shared__ unsigned int stage[2][NHT * 64 * 4];   // 2 x 10 KB double-buffered frags
  __shared__ unsigned int gi_lds[NE / 2];           // g_i as bf16 (1 KB)
  __shared__ alignas(16) float bias1[HP];           // hi[b,i,:] + b1
  __shared__ alignas(16) float bias2[HP];
  __shared__ alignas(16) float w3s[HP];

  const int tid = threadIdx.x;
  const int bi = blockIdx.x;
  const int b = bi >> 8, i = bi & 255;
  const int lane = tid & 63, wave = tid >> 6;
  const int c16 = lane & 15, quad = lane >> 4;

  // ---- phase 0: per-block constants into LDS ----
  {
    const u32x4* grow = (const u32x4*)(g_bf16 + (size_t)(b * NN + i) * NE);
    if (tid < 64) ((u32x4*)gi_lds)[tid] = grow[tid];
    if (tid >= 64 && tid < 64 + HP) {
      int h = tid - 64;
      bias1[h] = hi_pad[(size_t)(b * NN + i) * HP + h] + ((h < NH) ? b1[h] : 0.f);
      bias2[h] = (h < NH) ? b2[h] : 0.f;
      w3s[h]   = (h < NH) ? W3[h] : 0.f;
    }
  }
  __syncthreads();

  // ---- builder: A~[h,e] = g_i[e]*W1c[e,h] + W1b[e,h] in A-frag layout ----
  u32x4 wbR[2], wcR[2], giR[2];
  const int nr = (tid < 128) ? 2 : 1;   // 640 lane-rows per k-tile, 512 threads

  auto bld_load = [&](int kt) {
#pragma unroll
    for (int r = 0; r < 2; ++r) if (r < nr) {
      int row = tid + r * 512;
      int idx = kt * (NHT * 64) + row;
      wbR[r] = ((const u32x4*)WbF)[idx];
      wcR[r] = ((const u32x4*)WcF)[idx];
      giR[r] = ((const u32x4*)gi_lds)[kt * 4 + ((row & 63) >> 4)];
    }
  };
  auto bld_write = [&](int kt) {
    unsigned* dst = stage[kt & 1];
#pragma unroll
    for (int r = 0; r < 2; ++r) if (r < nr) {
      int row = tid + r * 512;
      u32x4 o;
#pragma unroll
      for (int q = 0; q < 4; ++q) {
        float lo = bf_lo(giR[r][q]) * bf_lo(wcR[r][q]) + bf_lo(wbR[r][q]);
        float hi = bf_hi(giR[r][q]) * bf_hi(wcR[r][q]) + bf_hi(wbR[r][q]);
        o[q] = pk_bf16(lo, hi);
      }
      ((u32x4*)dst)[row] = o;
    }
  };

  // ---- phase 1: D1[h][j] = A~ * g_j  (16x16x32 bf16 MFMA) ----
  f32x4 acc1[NHT][2] = {};
  const u32x4* gB = (const u32x4*)g_bf16;
  const int jbase = wave * 32 + c16;
  const size_t gidx0 = (size_t)(b * NN + jbase) * 64 + quad;  // u32x4 units

  bld_load(0); bld_write(0);
  __syncthreads();

  for (int kt = 0; kt < NKT; ++kt) {
    if (kt + 1 < NKT) bld_load(kt + 1);
    short8 bf0 = __builtin_bit_cast(short8, gB[gidx0 + (size_t)kt * 4]);
    short8 bf1 = __builtin_bit_cast(short8, gB[gidx0 + 16 * 64 + (size_t)kt * 4]);
    const u32x4* As = (const u32x4*)stage[kt & 1];
#pragma unroll
    for (int ht = 0; ht < NHT; ++ht) {
      short8 af = __builtin_bit_cast(short8, As[ht * 64 + lane]);
      acc1[ht][0] = __builtin_amdgcn_mfma_f32_16x16x32_bf16(af, bf0, acc1[ht][0], 0, 0, 0);
      acc1[ht][1] = __builtin_amdgcn_mfma_f32_16x16x32_bf16(af, bf1, acc1[ht][1], 0, 0, 0);
    }
    if (kt + 1 < NKT) bld_write(kt + 1);
    __syncthreads();
  }

  // ---- epilogue 1: h1 = relu(D1 + hi + b1), bf16, kept in registers ----
  // lane holds h = 16*ht + 4*quad + r, j = wave*32 + jt*16 + c16
  unsigned Hlo[NHT][2], Hhi[NHT][2];
#pragma unroll
  for (int ht = 0; ht < NHT; ++ht) {
    f32x4 bv = *(const f32x4*)(bias1 + ht * 16 + quad * 4);
#pragma unroll
    for (int jt = 0; jt < 2; ++jt) {
      f32x4 v = acc1[ht][jt];
      float r0 = fmaxf(v[0] + bv[0], 0.f);
      float r1 = fmaxf(v[1] + bv[1], 0.f);
      float r2 = fmaxf(v[2] + bv[2], 0.f);
      float r3 = fmaxf(v[3] + bv[3], 0.f);
      Hlo[ht][jt] = pk_bf16(r0, r1);
      Hhi[ht][jt] = pk_bf16(r2, r3);
    }
  }

  // ---- phase 2 staging: W2^T frag chunks (5 KB? 10 KB per k-step) ----
  u32x4 w2R[2];
  auto st2_load = [&](int s) {
#pragma unroll
    for (int r = 0; r < 2; ++r) if (r < nr)
      w2R[r] = ((const u32x4*)W2TF)[s * (NHT * 64) + tid + r * 512];
  };
  auto st2_write = [&](int s) {
    unsigned* dst = stage[s & 1];
#pragma unroll
    for (int r = 0; r < 2; ++r) if (r < nr)
      ((u32x4*)dst)[tid + r * 512] = w2R[r];
  };

  st2_load(0); st2_write(0);
  __syncthreads();

  // ---- phase 2: D2[h'][j] = W2^T * h1 ; h1 C-layout -> B-frag via shfl ----
  f32x4 acc2[NHT][2] = {};
  const int lA = ((lane >> 4) & 1) * 32 + c16;  // source lane for d0..3
  const int lB = lA + 16;                        // source lane for d4..7
  const bool selHi = ((lane >> 5) & 1) != 0;     // quads 2,3 take t=2s+1

#pragma unroll
  for (int s = 0; s < NS; ++s) {
    if (s + 1 < NS) st2_load(s + 1);
    short8 b2f[2];
#pragma unroll
    for (int jt = 0; jt < 2; ++jt) {
      unsigned a0 = (unsigned)__shfl((int)Hlo[2 * s][jt], lA);
      unsigned a1 = (unsigned)__shfl((int)Hhi[2 * s][jt], lA);
      unsigned a2 = (unsigned)__shfl((int)Hlo[2 * s][jt], lB);
      unsigned a3 = (unsigned)__shfl((int)Hhi[2 * s][jt], lB);
      unsigned d0 = (unsigned)__shfl((int)Hlo[2 * s + 1][jt], lA);
      unsigned d1 = (unsigned)__shfl((int)Hhi[2 * s + 1][jt], lA);
      unsigned d2 = (unsigned)__shfl((int)Hlo[2 * s + 1][jt], lB);
      unsigned d3 = (unsigned)__shfl((int)Hhi[2 * s + 1][jt], lB);
      u32x4 fr;
      fr[0] = selHi ? d0 : a0;
      fr[1] = selHi ? d1 : a1;
      fr[2] = selHi ? d2 : a2;
      fr[3] = selHi ? d3 : a3;
      b2f[jt] = __builtin_bit_cast(short8, fr);
    }
    const u32x4* A2 = (const u32x4*)stage[s & 1];
#pragma unroll
    for (int ht = 0; ht < NHT; ++ht) {
      short8 af = __builtin_bit_cast(short8, A2[ht * 64 + lane]);
      acc2[ht][0] = __builtin_amdgcn_mfma_f32_16x16x32_bf16(af, b2f[0], acc2[ht][0], 0, 0, 0);
      acc2[ht][1] = __builtin_amdgcn_mfma_f32_16x16x32_bf16(af, b2f[1], acc2[ht][1], 0, 0, 0);
    }
    if (s + 1 < NS) st2_write(s + 1);
    __syncthreads();
  }

  // ---- epilogue 2 + GEMM3: score[j] = sum_h' relu(D2 + b2)*W3 ----
  float part0 = 0.f, part1 = 0.f;
#pragma unroll
  for (int ht = 0; ht < NHT; ++ht) {
    f32x4 bv = *(const f32x4*)(bias2 + ht * 16 + quad * 4);
    f32x4 wv = *(const f32x4*)(w3s + ht * 16 + quad * 4);
    f32x4 v0 = acc2[ht][0], v1 = acc2[ht][1];
#pragma unroll
    for (int r = 0; r < 4; ++r) {
      part0 += fmaxf(v0[r] + bv[r], 0.f) * wv[r];
      part1 += fmaxf(v1[r] + bv[r], 0.f) * wv[r];
    }
  }
  part0 += __shfl_xor(part0, 16); part0 += __shfl_xor(part0, 32);
  part1 += __shfl_xor(part1, 16); part1 += __shfl_xor(part1, 32);

  const float mi = mention[b * NN + i];
  const float b3v = b3[0];
  float sc = (quad == 0) ? part0 : part1;
  if (quad < 2) {
    int j = wave * 32 + quad * 16 + c16;
    float mj = mention[b * NN + j];
    out[((size_t)(b * NN + i)) * NN + j] = (mi + mj + sc + b3v) * (1.f / 3.f);
  }
}

// ---------- launch ----------
extern "C" void kernel_launch(void* const* d_in, const int* in_sizes, int n_in,
                              void* d_out, int out_size, void* d_ws, size_t ws_size,
                              hipStream_t stream) {
  const float* g  = (const float*)d_in[0];
  const float* m  = (const float*)d_in[1];
  const float* W1 = (const float*)d_in[2];
  const float* b1 = (const float*)d_in[3];
  const float* W2 = (const float*)d_in[4];
  const float* b2 = (const float*)d_in[5];
  const float* W3 = (const float*)d_in[6];
  const float* b3 = (const float*)d_in[7];
  float* out = (float*)d_out;

  char* ws = (char*)d_ws;
  unsigned short* g_bf16 = (unsigned short*)(ws);             // 524288 B
  unsigned short* WbF    = (unsigned short*)(ws + 524288);    // 163840 B
  unsigned short* WcF    = (unsigned short*)(ws + 688128);    // 163840 B
  unsigned short* W2TF   = (unsigned short*)(ws + 851968);    //  51200 B
  float*          hi_pad = (float*)(ws + 903168);             // 327680 B (total ~1.20 MB)

  prep_pack<<<309, 256, 0, stream>>>(g, W1, W2, g_bf16, WbF, WcF, W2TF);
  prep_hi<<<64, 256, 0, stream>>>(g, W1, hi_pad);
  pair_main<<<512, 512, 0, stream>>>(m, b1, b2, W3, b3, g_bf16, WbF, WcF, W2TF, hi_pad, out);
}

// Round 2
// 153.000 us; speedup vs baseline: 1.0765x; 1.0765x over previous
//
#include <hip/hip_runtime.h>
#include <hip/hip_bf16.h>

// PairwiseScore: B=2, N=256, E=512, H=150 (padded to 160)
// out[b,i,j] = (m[b,i] + m[b,j] + MLP3(g_i, g_j)) / 3
//
// Fold: hij + hj = sum_e (g_i[e]*W1c[e,h] + W1b[e,h]) * g_j[e]
// R2 changes vs R1:
//  - single fused prep kernel (g->bf16, W packs, hi as per-row fp32 dot) — kills ~100us prep
//  - pair_main: 256-thr blocks, grid 1024 (j-half per block) -> 2+ independent
//    blocks/CU so barrier drains overlap (R1 had 1 block/CU, Mfma 16%)
//  - phase-2 W2^T staging via global_load_lds (16B) — no VGPR round-trip

typedef __attribute__((ext_vector_type(4))) float f32x4;
typedef __attribute__((ext_vector_type(4))) unsigned int u32x4;
typedef __attribute__((ext_vector_type(2))) unsigned int u32x2;
typedef __attribute__((ext_vector_type(8))) short short8;

#define NB 2
#define NN 256
#define NE 512
#define NH 150
#define HP 160      // padded H
#define NKT 16      // NE/32 k-tiles for GEMM1
#define NHT 10      // HP/16 h-tiles
#define NS 5        // HP/32 k-steps for GEMM2

// ---------- helpers ----------
__device__ __forceinline__ unsigned pk_bf16(float a, float b) {
  unsigned ua = __builtin_bit_cast(unsigned, a);
  unsigned ub = __builtin_bit_cast(unsigned, b);
  ua += 0x7fffu + ((ua >> 16) & 1u);
  ub += 0x7fffu + ((ub >> 16) & 1u);
  return (ua >> 16) | (ub & 0xffff0000u);
}
__device__ __forceinline__ float bf_lo(unsigned u) { return __builtin_bit_cast(float, u << 16); }
__device__ __forceinline__ float bf_hi(unsigned u) { return __builtin_bit_cast(float, u & 0xffff0000u); }

__device__ __forceinline__ void async_cp16(const unsigned* gsrc, unsigned* ldst) {
  __builtin_amdgcn_global_load_lds(
      (const __attribute__((address_space(1))) unsigned*)gsrc,
      (__attribute__((address_space(3))) unsigned*)ldst, 16, 0, 0);
}

// ---------- fused prep: grid 821 x 256 ----------
//  bid [0,256)    : g (f32) -> g_bf16
//  bid [256,296)  : W1b/W1c -> WbF/WcF frag-major [(kt*10+ht)*64+lane]*8
//  bid [296,309)  : W2^T -> W2TF frag-major [(s*10+ht)*64+lane]*8
//  bid [309,821)  : hi[n,h] = sum_e g[n,e]*W1a[e,h]  (one row per block, fp32)
__global__ __launch_bounds__(256) void prep_all(
    const float* __restrict__ g, const float* __restrict__ W1,
    const float* __restrict__ W2,
    unsigned short* __restrict__ g_bf16, unsigned short* __restrict__ WbF,
    unsigned short* __restrict__ WcF, unsigned short* __restrict__ W2TF,
    float* __restrict__ hi_pad)
{
  int bid = blockIdx.x, tid = threadIdx.x;
  if (bid < 256) {
    int t = bid * 256 + tid;                 // 65536 float4s = 262144 floats
    f32x4 v = ((const f32x4*)g)[t];
    u32x2 o; o[0] = pk_bf16(v[0], v[1]); o[1] = pk_bf16(v[2], v[3]);
    ((u32x2*)g_bf16)[t] = o;
  } else if (bid < 296) {
    int row = (bid - 256) * 256 + tid;       // 0..10239 = 16kt*10ht*64lane
    int kt = row / 640; int rem = row - kt * 640;
    int l = rem & 63; int chh = rem >> 6;
    int e = kt * 32 + (l >> 4) * 8;
    int h = chh * 16 + (l & 15);
    u32x4 ob, oc;
#pragma unroll
    for (int q = 0; q < 4; ++q) {
      int e0 = e + 2 * q, e1 = e0 + 1;
      float vb0 = 0.f, vb1 = 0.f, vc0 = 0.f, vc1 = 0.f;
      if (h < NH) {
        vb0 = W1[(512 + e0) * NH + h]; vb1 = W1[(512 + e1) * NH + h];
        vc0 = W1[(1024 + e0) * NH + h]; vc1 = W1[(1024 + e1) * NH + h];
      }
      ob[q] = pk_bf16(vb0, vb1); oc[q] = pk_bf16(vc0, vc1);
    }
    ((u32x4*)WbF)[row] = ob;
    ((u32x4*)WcF)[row] = oc;
  } else if (bid < 309) {
    int row = (bid - 296) * 256 + tid;       // < 3200 = 5s*10ht*64lane
    if (row < 3200) {
      int s = row / 640; int rem = row - s * 640;
      int l = rem & 63; int chh = rem >> 6;
      int k = s * 32 + (l >> 4) * 8;
      int hp = chh * 16 + (l & 15);
      u32x4 o;
#pragma unroll
      for (int q = 0; q < 4; ++q) {
        int k0 = k + 2 * q, k1 = k0 + 1;
        float v0 = (k0 < NH && hp < NH) ? W2[k0 * NH + hp] : 0.f;
        float v1 = (k1 < NH && hp < NH) ? W2[k1 * NH + hp] : 0.f;
        o[q] = pk_bf16(v0, v1);
      }
      ((u32x4*)W2TF)[row] = o;
    }
  } else {
    int n = bid - 309;                       // 0..511
    int h = tid;
    if (h < HP) {
      float r = 0.f;
      if (h < NH) {
        const float* gr = g + (size_t)n * NE;
        const float* wp = W1 + h;            // W1a rows 0..511
        float a0 = 0.f, a1 = 0.f, a2 = 0.f, a3 = 0.f;
        for (int e = 0; e < NE; e += 4) {
          a0 = fmaf(gr[e],     wp[(size_t)(e)     * NH], a0);
          a1 = fmaf(gr[e + 1], wp[(size_t)(e + 1) * NH], a1);
          a2 = fmaf(gr[e + 2], wp[(size_t)(e + 2) * NH], a2);
          a3 = fmaf(gr[e + 3], wp[(size_t)(e + 3) * NH], a3);
        }
        r = (a0 + a1) + (a2 + a3);
      }
      hi_pad[(size_t)n * HP + h] = r;
    }
  }
}

// ---------- main fused kernel: 256 threads, one block per (b,i,j-half) ----------
__global__ __launch_bounds__(256) void pair_main(
    const float* __restrict__ mention, const float* __restrict__ b1,
    const float* __restrict__ b2, const float* __restrict__ W3,
    const float* __restrict__ b3,
    const unsigned short* __restrict__ g_bf16,
    const unsigned short* __restrict__ WbF, const unsigned short* __restrict__ WcF,
    const unsigned short* __restrict__ W2TF, const float* __restrict__ hi_pad,
    float* __restrict__ out)
{
  __shared__ unsigned int stage[2][NHT * 64 * 4];   // 2 x 10 KB double-buffered frags
  __shared__ unsigned int gi_lds[NE / 2];           // g_i as bf16 (1 KB)
  __shared__ alignas(16) float bias1[HP];           // hi[b,i,:] + b1
  __shared__ alignas(16) float bias2[HP];
  __shared__ alignas(16) float w3s[HP];

  const int tid = threadIdx.x;
  const int bi = blockIdx.x >> 1;         // (b,i)
  const int jh = blockIdx.x & 1;          // j-half
  const int b = bi >> 8, i = bi & 255;
  const int lane = tid & 63, wave = tid >> 6;       // 4 waves
  const int c16 = lane & 15, quad = lane >> 4;

  // ---- phase 0: per-block constants into LDS ----
  {
    const u32x4* grow = (const u32x4*)(g_bf16 + (size_t)(b * NN + i) * NE);
    if (tid < 64) ((u32x4*)gi_lds)[tid] = grow[tid];
    if (tid >= 64 && tid < 64 + HP) {
      int h = tid - 64;
      bias1[h] = hi_pad[(size_t)(b * NN + i) * HP + h] + ((h < NH) ? b1[h] : 0.f);
      bias2[h] = (h < NH) ? b2[h] : 0.f;
      w3s[h]   = (h < NH) ? W3[h] : 0.f;
    }
  }
  __syncthreads();

  // ---- builder: A~[h,e] = g_i[e]*W1c[e,h] + W1b[e,h] in A-frag layout ----
  // 640 lane-rows per k-tile over 256 threads: rows tid, tid+256, tid+512(<640)
  u32x4 wbR[3], wcR[3], giR[3];

  auto bld_load = [&](int kt) {
#pragma unroll
    for (int r = 0; r < 3; ++r) {
      int row = tid + r * 256;
      if (row < 640) {
        int idx = kt * (NHT * 64) + row;
        wbR[r] = ((const u32x4*)WbF)[idx];
        wcR[r] = ((const u32x4*)WcF)[idx];
        giR[r] = ((const u32x4*)gi_lds)[kt * 4 + ((row & 63) >> 4)];
      }
    }
  };
  auto bld_write = [&](int kt) {
    unsigned* dst = stage[kt & 1];
#pragma unroll
    for (int r = 0; r < 3; ++r) {
      int row = tid + r * 256;
      if (row < 640) {
        u32x4 o;
#pragma unroll
        for (int q = 0; q < 4; ++q) {
          float lo = bf_lo(giR[r][q]) * bf_lo(wcR[r][q]) + bf_lo(wbR[r][q]);
          float hi = bf_hi(giR[r][q]) * bf_hi(wcR[r][q]) + bf_hi(wbR[r][q]);
          o[q] = pk_bf16(lo, hi);
        }
        ((u32x4*)dst)[row] = o;
      }
    }
  };

  // ---- phase 1: D1[h][j] = A~ * g_j  (16x16x32 bf16 MFMA) ----
  f32x4 acc1[NHT][2] = {};
  const u32x4* gB = (const u32x4*)g_bf16;
  const int jbase = jh * 128 + wave * 32 + c16;
  const size_t gidx0 = (size_t)(b * NN + jbase) * 64 + quad;  // u32x4 units

  bld_load(0); bld_write(0);
  __syncthreads();

  for (int kt = 0; kt < NKT; ++kt) {
    if (kt + 1 < NKT) bld_load(kt + 1);
    short8 bf0 = __builtin_bit_cast(short8, gB[gidx0 + (size_t)kt * 4]);
    short8 bf1 = __builtin_bit_cast(short8, gB[gidx0 + 16 * 64 + (size_t)kt * 4]);
    const u32x4* As = (const u32x4*)stage[kt & 1];
#pragma unroll
    for (int ht = 0; ht < NHT; ++ht) {
      short8 af = __builtin_bit_cast(short8, As[ht * 64 + lane]);
      acc1[ht][0] = __builtin_amdgcn_mfma_f32_16x16x32_bf16(af, bf0, acc1[ht][0], 0, 0, 0);
      acc1[ht][1] = __builtin_amdgcn_mfma_f32_16x16x32_bf16(af, bf1, acc1[ht][1], 0, 0, 0);
    }
    if (kt + 1 < NKT) bld_write(kt + 1);
    __syncthreads();
  }

  // ---- epilogue 1: h1 = relu(D1 + hi + b1), bf16, kept in registers ----
  // lane holds h = 16*ht + 4*quad + r, j = jh*128 + wave*32 + jt*16 + c16
  unsigned Hlo[NHT][2], Hhi[NHT][2];
#pragma unroll
  for (int ht = 0; ht < NHT; ++ht) {
    f32x4 bv = *(const f32x4*)(bias1 + ht * 16 + quad * 4);
#pragma unroll
    for (int jt = 0; jt < 2; ++jt) {
      f32x4 v = acc1[ht][jt];
      float r0 = fmaxf(v[0] + bv[0], 0.f);
      float r1 = fmaxf(v[1] + bv[1], 0.f);
      float r2 = fmaxf(v[2] + bv[2], 0.f);
      float r3 = fmaxf(v[3] + bv[3], 0.f);
      Hlo[ht][jt] = pk_bf16(r0, r1);
      Hhi[ht][jt] = pk_bf16(r2, r3);
    }
  }

  // ---- phase 2 staging: W2^T frags direct global->LDS (async, 16B) ----
  auto st2_issue = [&](int s) {
    unsigned* dst = stage[s & 1];
#pragma unroll
    for (int r = 0; r < 3; ++r) {
      int row = tid + r * 256;
      if (row < 640)
        async_cp16((const unsigned*)W2TF + (size_t)(s * 640 + row) * 4,
                   dst + row * 4);
    }
  };

  st2_issue(0);
  __syncthreads();

  // ---- phase 2: D2[h'][j] = W2^T * h1 ; h1 C-layout -> B-frag via shfl ----
  f32x4 acc2[NHT][2] = {};
  const int lA = ((lane >> 4) & 1) * 32 + c16;  // source lane for d0..3
  const int lB = lA + 16;                        // source lane for d4..7
  const bool selHi = ((lane >> 5) & 1) != 0;     // quads 2,3 take t=2s+1

#pragma unroll
  for (int s = 0; s < NS; ++s) {
    if (s + 1 < NS) st2_issue(s + 1);
    short8 b2f[2];
#pragma unroll
    for (int jt = 0; jt < 2; ++jt) {
      unsigned a0 = (unsigned)__shfl((int)Hlo[2 * s][jt], lA);
      unsigned a1 = (unsigned)__shfl((int)Hhi[2 * s][jt], lA);
      unsigned a2 = (unsigned)__shfl((int)Hlo[2 * s][jt], lB);
      unsigned a3 = (unsigned)__shfl((int)Hhi[2 * s][jt], lB);
      unsigned d0 = (unsigned)__shfl((int)Hlo[2 * s + 1][jt], lA);
      unsigned d1 = (unsigned)__shfl((int)Hhi[2 * s + 1][jt], lA);
      unsigned d2 = (unsigned)__shfl((int)Hlo[2 * s + 1][jt], lB);
      unsigned d3 = (unsigned)__shfl((int)Hhi[2 * s + 1][jt], lB);
      u32x4 fr;
      fr[0] = selHi ? d0 : a0;
      fr[1] = selHi ? d1 : a1;
      fr[2] = selHi ? d2 : a2;
      fr[3] = selHi ? d3 : a3;
      b2f[jt] = __builtin_bit_cast(short8, fr);
    }
    const u32x4* A2 = (const u32x4*)stage[s & 1];
#pragma unroll
    for (int ht = 0; ht < NHT; ++ht) {
      short8 af = __builtin_bit_cast(short8, A2[ht * 64 + lane]);
      acc2[ht][0] = __builtin_amdgcn_mfma_f32_16x16x32_bf16(af, b2f[0], acc2[ht][0], 0, 0, 0);
      acc2[ht][1] = __builtin_amdgcn_mfma_f32_16x16x32_bf16(af, b2f[1], acc2[ht][1], 0, 0, 0);
    }
    __syncthreads();
  }

  // ---- epilogue 2 + GEMM3: score[j] = sum_h' relu(D2 + b2)*W3 ----
  float part0 = 0.f, part1 = 0.f;
#pragma unroll
  for (int ht = 0; ht < NHT; ++ht) {
    f32x4 bv = *(const f32x4*)(bias2 + ht * 16 + quad * 4);
    f32x4 wv = *(const f32x4*)(w3s + ht * 16 + quad * 4);
    f32x4 v0 = acc2[ht][0], v1 = acc2[ht][1];
#pragma unroll
    for (int r = 0; r < 4; ++r) {
      part0 += fmaxf(v0[r] + bv[r], 0.f) * wv[r];
      part1 += fmaxf(v1[r] + bv[r], 0.f) * wv[r];
    }
  }
  part0 += __shfl_xor(part0, 16); part0 += __shfl_xor(part0, 32);
  part1 += __shfl_xor(part1, 16); part1 += __shfl_xor(part1, 32);

  const float mi = mention[b * NN + i];
  const float b3v = b3[0];
  float sc = (quad == 0) ? part0 : part1;
  if (quad < 2) {
    int j = jh * 128 + wave * 32 + quad * 16 + c16;
    float mj = mention[b * NN + j];
    out[((size_t)(b * NN + i)) * NN + j] = (mi + mj + sc + b3v) * (1.f / 3.f);
  }
}

// ---------- launch ----------
extern "C" void kernel_launch(void* const* d_in, const int* in_sizes, int n_in,
                              void* d_out, int out_size, void* d_ws, size_t ws_size,
                              hipStream_t stream) {
  const float* g  = (const float*)d_in[0];
  const float* m  = (const float*)d_in[1];
  const float* W1 = (const float*)d_in[2];
  const float* b1 = (const float*)d_in[3];
  const float* W2 = (const float*)d_in[4];
  const float* b2 = (const float*)d_in[5];
  const float* W3 = (const float*)d_in[6];
  const float* b3 = (const float*)d_in[7];
  float* out = (float*)d_out;

  char* ws = (char*)d_ws;
  unsigned short* g_bf16 = (unsigned short*)(ws);             // 524288 B
  unsigned short* WbF    = (unsigned short*)(ws + 524288);    // 163840 B
  unsigned short* WcF    = (unsigned short*)(ws + 688128);    // 163840 B
  unsigned short* W2TF   = (unsigned short*)(ws + 851968);    //  51200 B
  float*          hi_pad = (float*)(ws + 903168);             // 327680 B (total ~1.20 MB)

  prep_all<<<821, 256, 0, stream>>>(g, W1, W2, g_bf16, WbF, WcF, W2TF, hi_pad);
  pair_main<<<1024, 256, 0, stream>>>(m, b1, b2, W3, b3, g_bf16, WbF, WcF, W2TF, hi_pad, out);
}

// Round 3
// 116.280 us; speedup vs baseline: 1.4165x; 1.3158x over previous
//
#include <hip/hip_runtime.h>
#include <hip/hip_bf16.h>

// PairwiseScore: B=2, N=256, E=512, H=150 (padded to 160)
// out[b,i,j] = (m[b,i] + m[b,j] + MLP3(g_i, g_j)) / 3
//
// Fold: hij + hj = sum_e (g_i[e]*W1c[e,h] + W1b[e,h]) * g_j[e]
// R3 structure (one block per (b,i), 512 thr):
//  - hi computed IN-KERNEL via mini-MFMA with broadcast-B (g_i per k, all j cols)
//    -> prep_hi kernel deleted (it was ~50us latency-bound)
//  - A~ built ONE-SHOT per 8-kt mega-tile (80KB LDS, 10 rows/thread exactly),
//    then 160 uninterrupted MFMA/wave; 2 mega-phases -> 6 barriers total
//  - phase-2 W2^T staged async into freed A~ buffer, overlapped w/ epilogue-1;
//    phase-2 K-loop barrier-free. shfl C->B-frag transform kept verbatim.

typedef __attribute__((ext_vector_type(4))) float f32x4;
typedef __attribute__((ext_vector_type(4))) unsigned int u32x4;
typedef __attribute__((ext_vector_type(2))) unsigned int u32x2;
typedef __attribute__((ext_vector_type(8))) short short8;

#define NB 2
#define NN 256
#define NE 512
#define NH 150
#define HP 160      // padded H
#define NKT 16      // NE/32 k-tiles for GEMM1
#define NHT 10      // HP/16 h-tiles
#define NS 5        // HP/32 k-steps for GEMM2

// ---------- helpers ----------
__device__ __forceinline__ unsigned pk_bf16(float a, float b) {
  unsigned ua = __builtin_bit_cast(unsigned, a);
  unsigned ub = __builtin_bit_cast(unsigned, b);
  ua += 0x7fffu + ((ua >> 16) & 1u);
  ub += 0x7fffu + ((ub >> 16) & 1u);
  return (ua >> 16) | (ub & 0xffff0000u);
}
__device__ __forceinline__ float bf_lo(unsigned u) { return __builtin_bit_cast(float, u << 16); }
__device__ __forceinline__ float bf_hi(unsigned u) { return __builtin_bit_cast(float, u & 0xffff0000u); }

__device__ __forceinline__ void async_cp16(const unsigned* gsrc, unsigned* ldst) {
  __builtin_amdgcn_global_load_lds(
      (const __attribute__((address_space(1))) unsigned*)gsrc,
      (__attribute__((address_space(3))) unsigned*)ldst, 16, 0, 0);
}

// ---------- prep: grid 309 x 256 ----------
//  bid [0,256)    : g (f32) -> g_bf16
//  bid [256,296)  : W1a/W1b/W1c -> WaF/WbF/WcF frag-major [(kt*10+ht)*64+lane]*8
//  bid [296,309)  : W2^T -> W2TF frag-major [(s*10+ht)*64+lane]*8
__global__ __launch_bounds__(256) void prep_pack(
    const float* __restrict__ g, const float* __restrict__ W1,
    const float* __restrict__ W2,
    unsigned short* __restrict__ g_bf16, unsigned short* __restrict__ WaF,
    unsigned short* __restrict__ WbF, unsigned short* __restrict__ WcF,
    unsigned short* __restrict__ W2TF)
{
  int bid = blockIdx.x, tid = threadIdx.x;
  if (bid < 256) {
    int t = bid * 256 + tid;                 // 65536 float4s = 262144 floats
    f32x4 v = ((const f32x4*)g)[t];
    u32x2 o; o[0] = pk_bf16(v[0], v[1]); o[1] = pk_bf16(v[2], v[3]);
    ((u32x2*)g_bf16)[t] = o;
  } else if (bid < 296) {
    int row = (bid - 256) * 256 + tid;       // 0..10239 = 16kt*10ht*64lane
    int kt = row / 640; int rem = row - kt * 640;
    int l = rem & 63; int chh = rem >> 6;
    int e = kt * 32 + (l >> 4) * 8;
    int h = chh * 16 + (l & 15);
    u32x4 oa, ob, oc;
#pragma unroll
    for (int q = 0; q < 4; ++q) {
      int e0 = e + 2 * q, e1 = e0 + 1;
      float va0 = 0.f, va1 = 0.f, vb0 = 0.f, vb1 = 0.f, vc0 = 0.f, vc1 = 0.f;
      if (h < NH) {
        va0 = W1[(size_t)e0 * NH + h];          va1 = W1[(size_t)e1 * NH + h];
        vb0 = W1[(size_t)(512 + e0) * NH + h];  vb1 = W1[(size_t)(512 + e1) * NH + h];
        vc0 = W1[(size_t)(1024 + e0) * NH + h]; vc1 = W1[(size_t)(1024 + e1) * NH + h];
      }
      oa[q] = pk_bf16(va0, va1);
      ob[q] = pk_bf16(vb0, vb1);
      oc[q] = pk_bf16(vc0, vc1);
    }
    ((u32x4*)WaF)[row] = oa;
    ((u32x4*)WbF)[row] = ob;
    ((u32x4*)WcF)[row] = oc;
  } else {
    int row = (bid - 296) * 256 + tid;       // < 3200 = 5s*10ht*64lane
    if (row < 3200) {
      int s = row / 640; int rem = row - s * 640;
      int l = rem & 63; int chh = rem >> 6;
      int k = s * 32 + (l >> 4) * 8;
      int hp = chh * 16 + (l & 15);
      u32x4 o;
#pragma unroll
      for (int q = 0; q < 4; ++q) {
        int k0 = k + 2 * q, k1 = k0 + 1;
        float v0 = (k0 < NH && hp < NH) ? W2[(size_t)k0 * NH + hp] : 0.f;
        float v1 = (k1 < NH && hp < NH) ? W2[(size_t)k1 * NH + hp] : 0.f;
        o[q] = pk_bf16(v0, v1);
      }
      ((u32x4*)W2TF)[row] = o;
    }
  }
}

// ---------- main fused kernel: 512 threads, one block per (b,i) ----------
__global__ __launch_bounds__(512) void pair_main(
    const float* __restrict__ mention, const float* __restrict__ b1,
    const float* __restrict__ b2, const float* __restrict__ W3,
    const float* __restrict__ b3,
    const unsigned short* __restrict__ g_bf16,
    const unsigned short* __restrict__ WaF,
    const unsigned short* __restrict__ WbF, const unsigned short* __restrict__ WcF,
    const unsigned short* __restrict__ W2TF,
    float* __restrict__ out)
{
  __shared__ unsigned int stage[8 * NHT * 64 * 4];  // 80 KB: one-shot A~ mega-tile / W2TF
  __shared__ unsigned int gi_lds[NE / 2];           // g_i as bf16 (1 KB)
  __shared__ alignas(16) float bias1[HP];           // b1 + hi  (hi added via mini-MFMA)
  __shared__ alignas(16) float bias2[HP];
  __shared__ alignas(16) float w3s[HP];

  const int tid = threadIdx.x;
  const int bi = blockIdx.x;
  const int b = bi >> 8, i = bi & 255;
  const int lane = tid & 63, wave = tid >> 6;       // 8 waves
  const int c16 = lane & 15, quad = lane >> 4;

  // ---- phase 0: per-block constants into LDS ----
  {
    const u32x4* grow = (const u32x4*)(g_bf16 + (size_t)(b * NN + i) * NE);
    if (tid < 64) ((u32x4*)gi_lds)[tid] = grow[tid];
    if (tid < HP) {
      int h = tid;
      bias1[h] = (h < NH) ? b1[h] : 0.f;
      bias2[h] = (h < NH) ? b2[h] : 0.f;
      w3s[h]   = (h < NH) ? W3[h] : 0.f;
    }
  }
  __syncthreads();   // barrier A

  // ---- builder for one 8-kt mega-tile: exactly 10 rows/thread (5120 rows) ----
  auto build_mega = [&](int mega) {
#pragma unroll
    for (int r = 0; r < 10; ++r) {
      int v = tid + r * 512;                 // 0..5119
      int ktl = v / 640; int rem = v - ktl * 640;
      int l = rem & 63;
      int ktg = mega * 8 + ktl;
      int gidx = ktg * 640 + (rem >> 6) * 64 + l;
      u32x4 wb = ((const u32x4*)WbF)[gidx];
      u32x4 wc = ((const u32x4*)WcF)[gidx];
      u32x4 gi = ((const u32x4*)gi_lds)[ktg * 4 + (l >> 4)];
      u32x4 o;
#pragma unroll
      for (int q = 0; q < 4; ++q) {
        float lo = bf_lo(gi[q]) * bf_lo(wc[q]) + bf_lo(wb[q]);
        float hi = bf_hi(gi[q]) * bf_hi(wc[q]) + bf_hi(wb[q]);
        o[q] = pk_bf16(lo, hi);
      }
      ((u32x4*)stage)[v] = o;
    }
  };

  // ---- mega 0 build; waves 0-4 also compute hi via mini-MFMA (broadcast B) ----
  build_mega(0);
  if (wave < 5) {
    f32x4 ah0 = {}, ah1 = {};
#pragma unroll
    for (int kt = 0; kt < NKT; ++kt) {
      short8 bbc = __builtin_bit_cast(short8, ((const u32x4*)gi_lds)[kt * 4 + quad]);
      short8 a0 = __builtin_bit_cast(short8,
          ((const u32x4*)WaF)[(kt * NHT + 2 * wave) * 64 + lane]);
      short8 a1 = __builtin_bit_cast(short8,
          ((const u32x4*)WaF)[(kt * NHT + 2 * wave + 1) * 64 + lane]);
      ah0 = __builtin_amdgcn_mfma_f32_16x16x32_bf16(a0, bbc, ah0, 0, 0, 0);
      ah1 = __builtin_amdgcn_mfma_f32_16x16x32_bf16(a1, bbc, ah1, 0, 0, 0);
    }
    if (c16 == 0) {
#pragma unroll
      for (int r = 0; r < 4; ++r) {
        bias1[(2 * wave) * 16 + quad * 4 + r]     += ah0[r];
        bias1[(2 * wave + 1) * 16 + quad * 4 + r] += ah1[r];
      }
    }
  }
  __syncthreads();   // barrier B

  // ---- phase 1: D1[h][j] = A~ * g_j, two barrier-free mega-phases ----
  f32x4 acc1[NHT][2] = {};
  const u32x4* gB = (const u32x4*)g_bf16;
  const int jbase = wave * 32 + c16;
  const size_t gidx0 = (size_t)(b * NN + jbase) * 64 + quad;  // u32x4 units

#pragma unroll 1
  for (int mega = 0; mega < 2; ++mega) {
#pragma unroll 1
    for (int ktl = 0; ktl < 8; ++ktl) {
      int ktg = mega * 8 + ktl;
      short8 bf0 = __builtin_bit_cast(short8, gB[gidx0 + (size_t)ktg * 4]);
      short8 bf1 = __builtin_bit_cast(short8, gB[gidx0 + 16 * 64 + (size_t)ktg * 4]);
      const u32x4* As = (const u32x4*)stage + ktl * (NHT * 64);
#pragma unroll
      for (int ht = 0; ht < NHT; ++ht) {
        short8 af = __builtin_bit_cast(short8, As[ht * 64 + lane]);
        acc1[ht][0] = __builtin_amdgcn_mfma_f32_16x16x32_bf16(af, bf0, acc1[ht][0], 0, 0, 0);
        acc1[ht][1] = __builtin_amdgcn_mfma_f32_16x16x32_bf16(af, bf1, acc1[ht][1], 0, 0, 0);
      }
    }
    if (mega == 0) {
      __syncthreads();   // barrier C: mega-0 reads done
      build_mega(1);
      __syncthreads();   // barrier D: mega-1 A~ ready
    }
  }
  __syncthreads();       // barrier E: all stage reads done (free buffer for W2TF)

  // ---- stage W2^T frags async (3200 rows) into freed buffer; overlap epilogue ----
#pragma unroll
  for (int r = 0; r < 7; ++r) {
    int row = tid + r * 512;
    if (row < 3200)
      async_cp16((const unsigned*)W2TF + (size_t)row * 4, stage + row * 4);
  }

  // ---- epilogue 1: h1 = relu(D1 + hi + b1) -> bf16 in registers ----
  // lane holds h = 16*ht + 4*quad + r, j = wave*32 + jt*16 + c16
  unsigned Hlo[NHT][2], Hhi[NHT][2];
#pragma unroll
  for (int ht = 0; ht < NHT; ++ht) {
    f32x4 bv = *(const f32x4*)(bias1 + ht * 16 + quad * 4);
#pragma unroll
    for (int jt = 0; jt < 2; ++jt) {
      f32x4 v = acc1[ht][jt];
      float r0 = fmaxf(v[0] + bv[0], 0.f);
      float r1 = fmaxf(v[1] + bv[1], 0.f);
      float r2 = fmaxf(v[2] + bv[2], 0.f);
      float r3 = fmaxf(v[3] + bv[3], 0.f);
      Hlo[ht][jt] = pk_bf16(r0, r1);
      Hhi[ht][jt] = pk_bf16(r2, r3);
    }
  }
  __syncthreads();       // barrier F: drains async staging

  // ---- phase 2: D2[h'][j] = W2^T * h1 ; h1 C-layout -> B-frag via shfl ----
  f32x4 acc2[NHT][2] = {};
  const int lA = ((lane >> 4) & 1) * 32 + c16;  // source lane for d0..3
  const int lB = lA + 16;                        // source lane for d4..7
  const bool selHi = ((lane >> 5) & 1) != 0;     // quads 2,3 take t=2s+1

#pragma unroll
  for (int s = 0; s < NS; ++s) {
    short8 b2f[2];
#pragma unroll
    for (int jt = 0; jt < 2; ++jt) {
      unsigned a0 = (unsigned)__shfl((int)Hlo[2 * s][jt], lA);
      unsigned a1 = (unsigned)__shfl((int)Hhi[2 * s][jt], lA);
      unsigned a2 = (unsigned)__shfl((int)Hlo[2 * s][jt], lB);
      unsigned a3 = (unsigned)__shfl((int)Hhi[2 * s][jt], lB);
      unsigned d0 = (unsigned)__shfl((int)Hlo[2 * s + 1][jt], lA);
      unsigned d1 = (unsigned)__shfl((int)Hhi[2 * s + 1][jt], lA);
      unsigned d2 = (unsigned)__shfl((int)Hlo[2 * s + 1][jt], lB);
      unsigned d3 = (unsigned)__shfl((int)Hhi[2 * s + 1][jt], lB);
      u32x4 fr;
      fr[0] = selHi ? d0 : a0;
      fr[1] = selHi ? d1 : a1;
      fr[2] = selHi ? d2 : a2;
      fr[3] = selHi ? d3 : a3;
      b2f[jt] = __builtin_bit_cast(short8, fr);
    }
    const u32x4* A2 = (const u32x4*)stage + s * (NHT * 64);
#pragma unroll
    for (int ht = 0; ht < NHT; ++ht) {
      short8 af = __builtin_bit_cast(short8, A2[ht * 64 + lane]);
      acc2[ht][0] = __builtin_amdgcn_mfma_f32_16x16x32_bf16(af, b2f[0], acc2[ht][0], 0, 0, 0);
      acc2[ht][1] = __builtin_amdgcn_mfma_f32_16x16x32_bf16(af, b2f[1], acc2[ht][1], 0, 0, 0);
    }
  }

  // ---- epilogue 2 + GEMM3: score[j] = sum_h' relu(D2 + b2)*W3 ----
  float part0 = 0.f, part1 = 0.f;
#pragma unroll
  for (int ht = 0; ht < NHT; ++ht) {
    f32x4 bv = *(const f32x4*)(bias2 + ht * 16 + quad * 4);
    f32x4 wv = *(const f32x4*)(w3s + ht * 16 + quad * 4);
    f32x4 v0 = acc2[ht][0], v1 = acc2[ht][1];
#pragma unroll
    for (int r = 0; r < 4; ++r) {
      part0 += fmaxf(v0[r] + bv[r], 0.f) * wv[r];
      part1 += fmaxf(v1[r] + bv[r], 0.f) * wv[r];
    }
  }
  part0 += __shfl_xor(part0, 16); part0 += __shfl_xor(part0, 32);
  part1 += __shfl_xor(part1, 16); part1 += __shfl_xor(part1, 32);

  const float mi = mention[b * NN + i];
  const float b3v = b3[0];
  float sc = (quad == 0) ? part0 : part1;
  if (quad < 2) {
    int j = wave * 32 + quad * 16 + c16;
    float mj = mention[b * NN + j];
    out[((size_t)(b * NN + i)) * NN + j] = (mi + mj + sc + b3v) * (1.f / 3.f);
  }
}

// ---------- launch ----------
extern "C" void kernel_launch(void* const* d_in, const int* in_sizes, int n_in,
                              void* d_out, int out_size, void* d_ws, size_t ws_size,
                              hipStream_t stream) {
  const float* g  = (const float*)d_in[0];
  const float* m  = (const float*)d_in[1];
  const float* W1 = (const float*)d_in[2];
  const float* b1 = (const float*)d_in[3];
  const float* W2 = (const float*)d_in[4];
  const float* b2 = (const float*)d_in[5];
  const float* W3 = (const float*)d_in[6];
  const float* b3 = (const float*)d_in[7];
  float* out = (float*)d_out;

  char* ws = (char*)d_ws;
  unsigned short* g_bf16 = (unsigned short*)(ws);              // 524288 B
  unsigned short* WaF    = (unsigned short*)(ws + 524288);     // 163840 B
  unsigned short* WbF    = (unsigned short*)(ws + 688128);     // 163840 B
  unsigned short* WcF    = (unsigned short*)(ws + 851968);     // 163840 B
  unsigned short* W2TF   = (unsigned short*)(ws + 1015808);    //  51200 B (total ~1.02 MB)

  prep_pack<<<309, 256, 0, stream>>>(g, W1, W2, g_bf16, WaF, WbF, WcF, W2TF);
  pair_main<<<512, 512, 0, stream>>>(m, b1, b2, W3, b3, g_bf16, WaF, WbF, WcF, W2TF, out);
}